// Round 15
// baseline (370.261 us; speedup 1.0000x reference)
//
#include <hip/hip_runtime.h>

typedef short bf16x8 __attribute__((ext_vector_type(8)));
typedef float f32x4 __attribute__((ext_vector_type(4)));

#define NROWS 131072L
#define DIN 1024
#define DEMB 512
#define NEXT 640   // extended B rows: 512 emb + 34 folded-head + zero tail

__device__ __forceinline__ unsigned short f2bf(float f) {
  unsigned u = __float_as_uint(f);
  u += 0x7FFFu + ((u >> 16) & 1u);
  return (unsigned short)(u >> 16);
}

// Pack two f32 -> two bf16 (round-half-up): 2 adds + 1 v_perm_b32 (R5+-proven).
__device__ __forceinline__ unsigned pkhi(float a, float b) {
  unsigned ua = __float_as_uint(a) + 0x8000u;
  unsigned ub = __float_as_uint(b) + 0x8000u;
  return __builtin_amdgcn_perm(ub, ua, 0x07060302u);
}

__device__ __forceinline__ float softplusf(float v) {
  return fmaxf(v, 0.f) + log1pf(expf(-fabsf(v)));
}

// ---------- kernel 0: Wb (1024x512 f32) -> WbT rows 0..511 (bf16, k-contig) ----------
__global__ __launch_bounds__(256) void wb_transpose(const float* __restrict__ Wb,
                                                    unsigned short* __restrict__ WbT) {
  int g = blockIdx.x * 256 + threadIdx.x;
  int n = g & 511;
  int kb = g >> 9;
  unsigned short tmp[8];
#pragma unroll
  for (int j = 0; j < 8; ++j)
    tmp[j] = f2bf(Wb[(kb * 8 + j) * DEMB + n]);
  uint4 v;
  v.x = (unsigned)tmp[0] | ((unsigned)tmp[1] << 16);
  v.y = (unsigned)tmp[2] | ((unsigned)tmp[3] << 16);
  v.z = (unsigned)tmp[4] | ((unsigned)tmp[5] << 16);
  v.w = (unsigned)tmp[6] | ((unsigned)tmp[7] << 16);
  *(uint4*)(WbT + (long)n * DIN + kb * 8) = v;
}

// ---------- kernel 0b: zero rows 546..639 of WbT_ext ----------
__global__ void zero_tail(unsigned* __restrict__ p) {
  p[blockIdx.x * 256 + threadIdx.x] = 0u;
}

// ---------- kernel 0c: WbT rows 512..545 = (Wb @ W34)^T ----------
__global__ __launch_bounds__(256) void wfold_rows(const float* __restrict__ Wb,
                                                  const float* __restrict__ Wp,
                                                  const float* __restrict__ Ws,
                                                  unsigned short* __restrict__ WbT) {
  int w = threadIdx.x >> 6, lane = threadIdx.x & 63;
  int k = blockIdx.x * 4 + w;
  if (lane >= 34) return;
  const float* src;
  if (lane < 2) src = Wp + lane;
  else { int s = (lane - 2) >> 1; src = Ws + s * 1024 + (lane & 1); }
  const float* wrow = Wb + (long)k * DEMB;
  float acc = 0.f;
#pragma unroll 8
  for (int d = 0; d < DEMB; ++d) acc = fmaf(wrow[d], src[2 * d], acc);
  WbT[(long)(512 + lane) * DIN + k] = f2bf(acc);
}

// ---------- kernel 0d: bfold[j] = bb @ W34[:,j] + bias34[j] ----------
__global__ void bfold_k(const float* __restrict__ bb, const float* __restrict__ Wp,
                        const float* __restrict__ bp, const float* __restrict__ Ws,
                        const float* __restrict__ bs, float* __restrict__ bf) {
  int j = threadIdx.x;
  if (j >= 34) return;
  const float* src; float bias;
  if (j < 2) { src = Wp + j; bias = bp[j]; }
  else { int s = (j - 2) >> 1; src = Ws + s * 1024 + (j & 1); bias = bs[s * 2 + (j & 1)]; }
  float acc = bias;
  for (int d = 0; d < DEMB; ++d) acc = fmaf(bb[d], src[2 * d], acc);
  bf[j] = acc;
}

#define SB __builtin_amdgcn_sched_barrier(0)

// ---------- kernel 1: fused GEMM — R13 geometry, stall-free phase ----------
// 128x128 tile, BK=64, 2x2 waves. B: 3 LDS slots, staged 2 phases ahead.
// A: 2 reg bufs (2 ahead) + 2 LDS slots; writeA BEFORE compute (latency hides
// under 32 MFMA). ONE mid-phase vmcnt(12) (drains {B(t+1),A(t+1)}, issued
// 1-2 phases ago); lgkm0+barrier at phase end. No post-compute VMEM stall.
__global__ __launch_bounds__(256, 2) void gemm_fused(
    const float* __restrict__ x, const unsigned short* __restrict__ wbt,
    const float* __restrict__ bb, const int* __restrict__ sid,
    const float* __restrict__ bfold, float* __restrict__ out) {
  __shared__ __align__(16) char SM[81920];   // As0|As1 (16K ea) | Bs0|Bs1|Bs2 (16K ea)
  char* const As0 = SM;
  char* const As1 = SM + 16384;
  char* const Bs0 = SM + 32768;
  char* const Bs1 = SM + 49152;
  char* const Bs2 = SM + 65536;

  const int t = threadIdx.x;
  const int lane = t & 63;
  const int wid = t >> 6;
  const int wm = wid >> 1, wn = wid & 1;

  // XCD swizzle: 5120 blocks (%8==0); 5 consecutive swz share one mtile/XCD.
  const int bid = blockIdx.x;
  const int swz = (bid & 7) * 640 + (bid >> 3);
  const int mtile = swz / 5;
  const int ntile = swz - mtile * 5;         // 0..3 emb, 4 = head
  const long m0 = (long)mtile * 128;
  const int n0 = ntile * 128;

  // ---- A staging (R1/R13-proven BK=64): row = t>>4 (+p*16), 16B-col t&15 ----
  const int arow = t >> 4;
  const int acol8 = (t & 15) * 8;
  const int abyte = arow * 128 + (acol8 ^ ((arow & 7) << 4));   // +p*2048
  const float* xbase = x + (m0 + arow) * DIN + (t & 15) * 4;

  // ---- B staging (R1/R13-proven): gload_lds, pre-swizzled source ----
  const int bn = wid * 32 + (lane >> 3);
  const int bg = (lane & 7) ^ (lane >> 3);
  const unsigned short* bsrc = wbt + (long)(n0 + bn) * DIN + bg * 8;

  // ---- fragment reads: granule = (ks*4+lg) ^ (l15&7), 128B rows ----
  const int l15 = lane & 15, lg = lane >> 4;
  const int s3 = lane & 7;
  const int kg0 = ((lg ^ s3) << 4);
  const int ardrow = (wm * 64 + l15) * 128;
  const int brdrow = (wn * 64 + l15) * 128;

  f32x4 acc[4][4] = {};
  float4 aA[8], aB[8];

  auto loadA = [&](float4* d, int k0) {
#pragma unroll
    for (int p = 0; p < 8; ++p)
      d[p] = *(const float4*)(xbase + (long)p * 16 * DIN + k0);
  };
  auto stageB = [&](char* Bw, int k0) {
#pragma unroll
    for (int i = 0; i < 4; ++i) {
      const unsigned short* gp = bsrc + (long)i * 8 * DIN + k0;
      __builtin_amdgcn_global_load_lds(
          (const __attribute__((address_space(1))) void*)gp,
          (__attribute__((address_space(3))) void*)(Bw + wid * 4096 + i * 1024),
          16, 0, 0);
    }
  };
  auto writeA = [&](char* Aw, const float4* d) {
#pragma unroll
    for (int p = 0; p < 8; ++p) {
      uint2 v;
      v.x = pkhi(d[p].x, d[p].y);
      v.y = pkhi(d[p].z, d[p].w);
      *(uint2*)(Aw + abyte + p * 2048) = v;
    }
  };
  auto compute = [&](const char* Ac, const char* Bc) {   // 16 ds_read + 32 MFMA
#pragma unroll
    for (int ks = 0; ks < 2; ++ks) {
      const int kgo = kg0 ^ (ks << 6);
      bf16x8 af[4], bfv[4];
#pragma unroll
      for (int i = 0; i < 4; ++i) {
        af[i]  = *(const bf16x8*)(Ac + ardrow + i * 2048 + kgo);
        bfv[i] = *(const bf16x8*)(Bc + brdrow + i * 2048 + kgo);
      }
      __builtin_amdgcn_s_setprio(1);
#pragma unroll
      for (int mi = 0; mi < 4; ++mi)
#pragma unroll
        for (int ni = 0; ni < 4; ++ni)
          acc[mi][ni] = __builtin_amdgcn_mfma_f32_16x16x32_bf16(af[mi], bfv[ni],
                                                               acc[mi][ni], 0, 0, 0);
      __builtin_amdgcn_s_setprio(0);
    }
  };

  // phase t: stage B(t+2); load A(t+2); vmcnt(12) [{B(t+1),A(t+1)} done];
  // writeA(A(t+1)); compute(t); lgkm0; barrier.
#define PH(BST, ALD, AWS, AWB, AC, BC, TT)                          \
  stageB(BST, ((TT) + 2) * 64);                                     \
  loadA(ALD, ((TT) + 2) * 64);                                      \
  SB; asm volatile("s_waitcnt vmcnt(12)" ::: "memory"); SB;         \
  writeA(AWS, AWB);                                                 \
  compute(AC, BC);                                                  \
  SB; asm volatile("s_waitcnt lgkmcnt(0)" ::: "memory"); SB;        \
  __builtin_amdgcn_s_barrier();

  // ---- prologue: B(0),B(1),A(0),A(1) issued; A(0) written; barrier ----
  stageB(Bs0, 0);
  stageB(Bs1, 64);
  loadA(aA, 0);
  loadA(aB, 64);
  SB; asm volatile("s_waitcnt vmcnt(8)" ::: "memory"); SB;   // B0,B1,A0 done; A1 flying
  writeA(As0, aA);
  SB; asm volatile("s_waitcnt lgkmcnt(0)" ::: "memory"); SB;
  __builtin_amdgcn_s_barrier();

  // ---- main loop: phases 0..11 (period-6 slot rotation), then 12,13 ----
#pragma unroll 1
  for (int tb = 0; tb < 12; tb += 6) {
    PH(Bs2, aA, As1, aB, As0, Bs0, tb + 0)
    PH(Bs0, aB, As0, aA, As1, Bs1, tb + 1)
    PH(Bs1, aA, As1, aB, As0, Bs2, tb + 2)
    PH(Bs2, aB, As0, aA, As1, Bs0, tb + 3)
    PH(Bs0, aA, As1, aB, As0, Bs1, tb + 4)
    PH(Bs1, aB, As0, aA, As1, Bs2, tb + 5)
  }
  PH(Bs2, aA, As1, aB, As0, Bs0, 12)
  PH(Bs0, aB, As0, aA, As1, Bs1, 13)
#undef PH

  // ---- phase 14: no issues; drain all; write A(15); compute 14 ----
  SB; asm volatile("s_waitcnt vmcnt(0)" ::: "memory"); SB;   // B(15)+A(15) done
  writeA(As1, aB);                                           // A(15) from buf aB
  compute(As0, Bs2);                                         // tile 14 reads Bs[14%3=2]
  SB; asm volatile("s_waitcnt lgkmcnt(0)" ::: "memory"); SB;
  __builtin_amdgcn_s_barrier();
  // ---- phase 15 ----
  compute(As1, Bs0);                                         // tile 15 reads Bs[15%3=0]

  // ---- epilogue ----
  if (ntile < 4) {
    const int colg = n0 + wn * 64 + l15;
    float bbv[4];
#pragma unroll
    for (int ni = 0; ni < 4; ++ni) bbv[ni] = bb[colg + ni * 16];
#pragma unroll
    for (int mi = 0; mi < 4; ++mi) {
      const long rbase = m0 + wm * 64 + mi * 16 + lg * 4;
#pragma unroll
      for (int ni = 0; ni < 4; ++ni)
#pragma unroll
        for (int r = 0; r < 4; ++r)
          out[(rbase + r) * DEMB + colg + ni * 16] = acc[mi][ni][r] + bbv[ni];
    }
  } else {
    // head tile: acc cols 0..33 are x@Wfold; gather per-row selected cols via LDS
    __syncthreads();
    float* hl = (float*)SM;                  // [128][35] f32 = 17.5 KiB overlay
    if (wn == 0) {
#pragma unroll
      for (int ni = 0; ni < 3; ++ni) {
#pragma unroll
        for (int mi = 0; mi < 4; ++mi)
#pragma unroll
          for (int r = 0; r < 4; ++r) {
            int row = wm * 64 + mi * 16 + lg * 4 + r;
            int col = l15 + ni * 16;
            if (col < 35) hl[row * 35 + col] = acc[mi][ni][r];
          }
      }
    }
    __syncthreads();
    if (t < 128) {
      const long row = m0 + t;
      const int s = sid[row];
      const float v0 = hl[t * 35 + 0] + bfold[0];
      const float v1 = hl[t * 35 + 1] + bfold[1];
      const float v2 = hl[t * 35 + 2 + 2 * s] + bfold[2 + 2 * s];
      const float v3 = hl[t * 35 + 3 + 2 * s] + bfold[3 + 2 * s];
      float* hp = out + NROWS * DEMB;
      hp[row] = v0;
      hp[NROWS + row] = softplusf(v1) + 0.001f;
      hp[2 * NROWS + row] = v2;
      hp[3 * NROWS + row] = softplusf(v3) + 0.001f;
    }
  }
}

extern "C" void kernel_launch(void* const* d_in, const int* in_sizes, int n_in,
                              void* d_out, int out_size, void* d_ws, size_t ws_size,
                              hipStream_t stream) {
  const float* x  = (const float*)d_in[0];
  const int* sid  = (const int*)d_in[1];
  const float* Wb = (const float*)d_in[2];
  const float* bb = (const float*)d_in[3];
  const float* Wp = (const float*)d_in[4];
  const float* bp = (const float*)d_in[5];
  const float* Ws = (const float*)d_in[6];
  const float* bs = (const float*)d_in[7];
  float* out = (float*)d_out;
  unsigned short* WbT = (unsigned short*)d_ws;            // 640*1024 bf16 = 1.25 MiB
  float* bfoldp = (float*)(WbT + (long)NEXT * DIN);       // 34 f32

  wb_transpose<<<256, 256, 0, stream>>>(Wb, WbT);
  zero_tail<<<188, 256, 0, stream>>>((unsigned*)(WbT + 546 * DIN));
  wfold_rows<<<256, 256, 0, stream>>>(Wb, Wp, Ws, WbT);
  bfold_k<<<1, 64, 0, stream>>>(bb, Wp, bp, Ws, bs, bfoldp);
  gemm_fused<<<5120, 256, 0, stream>>>(x, WbT, bb, sid, bfoldp, out);
}